// Round 1
// 84.004 us; speedup vs baseline: 1.0007x; 1.0007x over previous
//
#include <hip/hip_runtime.h>
#include <math.h>

#define NPATCH 128
#define CH 8              // channels per patch = L / N_PATCHES
#define D 64
#define G 8               // query patches per block
#define NQ (G*CH)         // 64 queries/block
#define NKEY 128          // staged key slots
#define KSTR 72           // f16 strides: 72,136 ≡ 4 (mod 8) dwords; 100 -> 2-way max
#define VSTR 136
#define PSTR 100          // per-wave-relative P row: 96 keys + pad

typedef __fp16 half8 __attribute__((ext_vector_type(8)));
typedef float  f32x4 __attribute__((ext_vector_type(4)));
typedef unsigned u32x4 __attribute__((ext_vector_type(4)));

static __device__ __forceinline__ unsigned pk(float x, float y) {
    return __builtin_bit_cast(unsigned, __builtin_amdgcn_cvt_pkrtz(x, y));
}
static __device__ __forceinline__ half8 ld8(const unsigned short* p) {
    return __builtin_bit_cast(half8, *(const u32x4*)p);
}
static __device__ __forceinline__ half8 mk8(const float4& a, const float4& b) {
    u32x4 u = { pk(a.x, a.y), pk(a.z, a.w), pk(b.x, b.y), pk(b.z, b.w) };
    return __builtin_bit_cast(half8, u);
}

__global__ __launch_bounds__(256) void signed_attn_kernel(
    const float* __restrict__ Q, const float* __restrict__ K,
    const float* __restrict__ V, const float* __restrict__ logscale,
    float* __restrict__ O)
{
    __shared__ __align__(16) unsigned short sK[NKEY * KSTR];   // 18432 B
    __shared__ __align__(16) unsigned short sVt[D * VSTR];     // 17408 B (V transposed)
    __shared__ __align__(16) unsigned short sP[NQ * PSTR];     // 12800 B (wave-relative)
    // total 48640 B -> 3 blocks/CU (grid only needs 2/CU -> all 512 blocks co-resident)

    const int tid = threadIdx.x;
    const int grp = blockIdx.x & 15;          // 16 patch-groups
    const int bh  = blockIdx.x >> 4;
    const int p0  = grp * G;

    const long long base = (long long)bh * (NPATCH * CH) * D;
    const int nst = min(NKEY, (NPATCH - 1 - p0) * CH);   // valid staged keys (multiple of 8, >=56)

    const int wav = tid >> 6, lane = tid & 63;
    const int col = lane & 15, quad = lane >> 4;

    // ================= issue ALL global loads first (single vmcnt window) =================
    // Branch-free clamped addressing so the compiler can hoist every load above the
    // convert/ds_write chain: one overlapped latency epoch instead of three.
    const float4* Kg  = (const float4*)(K + base + (long long)((p0 + 1) * CH) * D);
    const float4* Vg  = (const float4*)(V + base + (long long)((p0 + 1) * CH) * D);
    const float4* Qg4 = (const float4*)(Q + base + (long long)(p0 * CH + wav * 16 + col) * D);

    float4 kr_[8];
#pragma unroll
    for (int it = 0; it < 8; ++it) {          // K tile: 128 rows x 16 dword-quads
        const int i = tid + it * 256;
        const int row = i >> 4, d4 = i & 15;
        kr_[it] = Kg[min(row, nst - 1) * 16 + d4];
    }
    float4 va_[4], vb_[4];
#pragma unroll
    for (int it = 0; it < 4; ++it) {          // V tile: (keypair, dim-quad)
        const int u = tid + it * 256;
        const int kp = u & 63, dq = u >> 6;
        const int k2 = min(2 * kp, nst - 2);  // nst is a multiple of 8 -> k2 even, valid pair
        va_[it] = Vg[k2 * 16 + dq];
        vb_[it] = Vg[(k2 + 1) * 16 + dq];
    }
    const float4 q0 = Qg4[quad * 2],     q1 = Qg4[quad * 2 + 1];
    const float4 q2 = Qg4[8 + quad * 2], q3 = Qg4[9 + quad * 2];
    const float ls = logscale[0];

    // ================= convert + LDS stores =================
#pragma unroll
    for (int it = 0; it < 8; ++it) {
        const int i = tid + it * 256;
        const int row = i >> 4, d4 = i & 15;
        uint2 w = make_uint2(0u, 0u);
        if (row < nst) w = make_uint2(pk(kr_[it].x, kr_[it].y), pk(kr_[it].z, kr_[it].w));
        *(uint2*)&sK[row * KSTR + d4 * 4] = w;
    }
#pragma unroll
    for (int it = 0; it < 4; ++it) {
        const int u = tid + it * 256;
        const int kp = u & 63, dq = u >> 6;
        float4 A = va_[it], Bv = vb_[it];
        if (2 * kp >= nst) { A = make_float4(0.f, 0.f, 0.f, 0.f); Bv = A; }
        *(unsigned*)&sVt[(dq * 4 + 0) * VSTR + 2 * kp] = pk(A.x, Bv.x);
        *(unsigned*)&sVt[(dq * 4 + 1) * VSTR + 2 * kp] = pk(A.y, Bv.y);
        *(unsigned*)&sVt[(dq * 4 + 2) * VSTR + 2 * kp] = pk(A.z, Bv.z);
        *(unsigned*)&sVt[(dq * 4 + 3) * VSTR + 2 * kp] = pk(A.w, Bv.w);
    }

    // ---- Q A-frags straight from registers (L1-resident; no LDS round-trip) ----
    const half8 a0 = mk8(q0, q1);             // d = 8q..8q+7
    const half8 a1 = mk8(q2, q3);             // d = 32+8q..+7

    // fold log2(e) into scale once: softmax uses raw v_exp_f32 (exp2) below
    const float scale = fminf(fmaxf(__expf(ls), 1.0f), 30.0f) * 0.125f;
    const float s2 = scale * 1.44269504088896f;

    __syncthreads();   // the only barrier

    // ---- QK^T: wave w needs keys [16w, 16w+80) -> 5 n-tiles ----
    f32x4 acc[5];
#pragma unroll
    for (int t = 0; t < 5; ++t) acc[t] = (f32x4){0.f, 0.f, 0.f, 0.f};
#pragma unroll
    for (int t = 0; t < 5; ++t) {
        const int krow = (wav + t) * 16 + col;
        const half8 b0 = ld8(&sK[krow * KSTR + quad * 8]);
        const half8 b1 = ld8(&sK[krow * KSTR + 32 + quad * 8]);
        acc[t] = __builtin_amdgcn_mfma_f32_16x16x32_f16(a0, b0, acc[t], 0, 0, 0);
        acc[t] = __builtin_amdgcn_mfma_f32_16x16x32_f16(a1, b1, acc[t], 0, 0, 0);
    }

    // ---- dual softmax (base-2): lane holds rows quad*4+r, abs cols 16(w+t)+col ----
#pragma unroll
    for (int r = 0; r < 4; ++r) {
        const int q   = wav * 16 + quad * 4 + r;          // block-local query
        const int kr0 = (q >> 3) * 8;                     // window start (16w or 16w+8)
        const int kmx = min(kr0 + 72, nst);

        float tv[5]; bool vl[5];
        float mp = -1e30f, mn = -1e30f;
#pragma unroll
        for (int t = 0; t < 5; ++t) {
            const int c = (wav + t) * 16 + col;
            tv[t] = s2 * acc[t][r];                       // log2-domain score
            vl[t] = (c >= kr0) && (c < kmx);
            mp = fmaxf(mp, vl[t] ?  tv[t] : -1e30f);
            mn = fmaxf(mn, vl[t] ? -tv[t] : -1e30f);
        }
#pragma unroll
        for (int off = 1; off < 16; off <<= 1) {
            mp = fmaxf(mp, __shfl_xor(mp, off));
            mn = fmaxf(mn, __shfl_xor(mn, off));
        }
        float ep[5], en[5], sp = 0.f, sn = 0.f;
#pragma unroll
        for (int t = 0; t < 5; ++t) {
            ep[t] = vl[t] ? __builtin_amdgcn_exp2f( tv[t] - mp) : 0.f;
            en[t] = vl[t] ? __builtin_amdgcn_exp2f(-tv[t] - mn) : 0.f;
            sp += ep[t]; sn += en[t];
        }
#pragma unroll
        for (int off = 1; off < 16; off <<= 1) {
            sp += __shfl_xor(sp, off);
            sn += __shfl_xor(sn, off);
        }
        const float rp = (sp > 0.f) ? 1.f / sp : 0.f;     // fully-masked row -> P = 0
        const float rn = (sn > 0.f) ? 1.f / sn : 0.f;
#pragma unroll
        for (int t = 0; t < 5; ++t) {                     // rel col = 16t+col
            const float A = ep[t] * rp - en[t] * rn;      // invalid -> exact 0
            sP[q * PSTR + t * 16 + col] = (unsigned short)pk(A, A);
        }
        sP[q * PSTR + 80 + col] = 0;                      // zero-pad rel cols 80..95
    }
    // wave reads back only its own 16 P rows -> no barrier needed

    // ---- PV: O[16 x 64] = P[16 x 96] * Vt^T (abs key = 16w + rel) ----
    f32x4 oc[4];
#pragma unroll
    for (int t = 0; t < 4; ++t) oc[t] = (f32x4){0.f, 0.f, 0.f, 0.f};
#pragma unroll
    for (int kq = 0; kq < 3; ++kq) {
        const half8 ap = ld8(&sP[(wav * 16 + col) * PSTR + kq * 32 + quad * 8]);
        // abs key base; clamp to <=120 so reads stay in the WRITTEN region of sVt.
        // Clamped lanes (wave 3, kq 2, quad>=2) have P==0, so any finite value is fine.
        const int kb = wav * 16 + kq * 32 + quad * 8;
        const int kcl = (kb <= 120) ? kb : 120;
#pragma unroll
        for (int t = 0; t < 4; ++t) {
            const half8 bv = ld8(&sVt[(t * 16 + col) * VSTR + kcl]);
            oc[t] = __builtin_amdgcn_mfma_f32_16x16x32_f16(ap, bv, oc[t], 0, 0, 0);
        }
    }

    // ---- store O: lane holds rows quad*4+r, cols col+16t ----
    float* Ob = O + base + (long long)(p0 * CH) * D;
#pragma unroll
    for (int t = 0; t < 4; ++t) {
#pragma unroll
        for (int r = 0; r < 4; ++r) {
            Ob[(wav * 16 + quad * 4 + r) * D + t * 16 + col] = oc[t][r];
        }
    }
}

extern "C" void kernel_launch(void* const* d_in, const int* in_sizes, int n_in,
                              void* d_out, int out_size, void* d_ws, size_t ws_size,
                              hipStream_t stream) {
    const float* Q  = (const float*)d_in[0];
    const float* K  = (const float*)d_in[1];
    const float* V  = (const float*)d_in[2];
    const float* ls = (const float*)d_in[3];
    float* O = (float*)d_out;

    const int L = 1024;
    const int nBH = in_sizes[0] / (L * D);    // B*H = 32
    dim3 grid(nBH * (NPATCH / G));            // 512 blocks
    signed_attn_kernel<<<grid, 256, 0, stream>>>(Q, K, V, ls, O);
}